// Round 3
// baseline (252.783 us; speedup 1.0000x reference)
//
#include <hip/hip_runtime.h>
#include <math.h>

#define NB 2
#define NC 128
#define NN 4096
#define FLT_MAX_BITS 0x7F7FFFFFu
#define L2E 1.44269504088896340736f

typedef __attribute__((ext_vector_type(8))) short short8;
typedef __attribute__((ext_vector_type(4))) float f32x4;

// bf16 copies, pre-transposed to [n][k] so MFMA fragments are k-contiguous.
__device__ unsigned short g_Tb[NB][NN][NC];
__device__ unsigned short g_Sb[NB][NN][NC];
__device__ float    g_tsqr[NB][NN];
__device__ float    g_ssqr[NB][NN];
__device__ unsigned g_rowmin[NB][NN];
__device__ unsigned g_colmin[NB][NN];
__device__ float    g_ZA[NB][NN];
__device__ float    g_ZB[NB][NN];
__device__ unsigned g_mA[NB][NN];
__device__ unsigned g_mB[NB][NN];

__device__ __forceinline__ unsigned f2bf(float f) {
    unsigned u = __float_as_uint(f);
    u += 0x7FFFu + ((u >> 16) & 1u);   // RNE
    return u >> 16;
}

// fp32 [k][n] -> bf16 [n][k], fused with squared-norm computation.
__global__ void __launch_bounds__(256) transpose_prep(const float* __restrict__ src,
                                                      const float* __restrict__ tgt) {
    __shared__ float ls[NC][68];
    int bid = blockIdx.x;              // 2 mat x 2 b x 64 n-chunks = 256
    int mat = bid >> 7;
    int b   = (bid >> 6) & 1;
    int n0  = (bid & 63) << 6;
    int tid = threadIdx.x;
    const float* in = (mat ? tgt : src) + (size_t)b * NC * NN;
    unsigned short (*out)[NC] = mat ? g_Tb[b] : g_Sb[b];
    float* sq = mat ? g_tsqr[b] : g_ssqr[b];

    for (int idx = tid; idx < NC * 16; idx += 256) {
        int k = idx >> 4, c4 = (idx & 15) << 2;
        *(float4*)&ls[k][c4] = *(const float4*)(in + (size_t)k * NN + n0 + c4);
    }
    __syncthreads();
    {
        int n = tid & 63, c = tid >> 6;
        for (int cc = c; cc < 16; cc += 4) {
            unsigned uo[4];
            #pragma unroll
            for (int e = 0; e < 4; ++e) {
                unsigned lo = f2bf(ls[cc * 8 + 2 * e][n]);
                unsigned hi = f2bf(ls[cc * 8 + 2 * e + 1][n]);
                uo[e] = lo | (hi << 16);
            }
            *(uint4*)&out[n0 + n][cc * 8] = make_uint4(uo[0], uo[1], uo[2], uo[3]);
        }
    }
    if (tid < 64) {
        float s = 0.f;
        #pragma unroll 8
        for (int k = 0; k < NC; ++k) { float v = ls[k][tid]; s = fmaf(v, v, s); }
        sq[n0 + tid] = s;
    }
}

__global__ void init_kernel() {
    int idx = blockIdx.x * 256 + threadIdx.x;   // 32 blocks
    int b = idx >> 12, i = idx & (NN - 1);
    g_rowmin[b][i] = FLT_MAX_BITS;  g_colmin[b][i] = FLT_MAX_BITS;
    g_ZA[b][i] = 0.f;  g_ZB[b][i] = 0.f;
    g_mA[b][i] = 0u;   g_mB[b][i] = 0u;
}

// Recompute D = ||t||^2 + ||s||^2 - 2 T S^T via MFMA each sweep (bit-identical
// across sweeps), fused with the per-sweep reduction. No D materialization.
// PASS 1: row/col mins.  PASS 2: Z sums.  PASS 3: normalized maxes.
template<int PASS>
__global__ void __launch_bounds__(256) sweep_kernel() {
    int bid = blockIdx.x;              // NB*32*32 = 2048
    int b  = bid >> 10;
    int ti = (bid >> 5) & 31, tj = bid & 31;
    int wave = threadIdx.x >> 6, lane = threadIdx.x & 63;
    int q = lane >> 4, x = lane & 15;
    int iw = ti * 128 + (wave >> 1) * 64;
    int jw = tj * 128 + (wave & 1) * 64;

    f32x4 acc[4][4];
    #pragma unroll
    for (int m = 0; m < 4; ++m)
        #pragma unroll
        for (int n = 0; n < 4; ++n)
            acc[m][n] = (f32x4){0.f, 0.f, 0.f, 0.f};

    #pragma unroll
    for (int kk = 0; kk < 4; ++kk) {
        int ko = kk * 32 + q * 8;
        short8 af[4], bfr[4];
        #pragma unroll
        for (int m = 0; m < 4; ++m)
            af[m] = *(const short8*)&g_Tb[b][iw + m * 16 + x][ko];
        #pragma unroll
        for (int n = 0; n < 4; ++n)
            bfr[n] = *(const short8*)&g_Sb[b][jw + n * 16 + x][ko];
        #pragma unroll
        for (int m = 0; m < 4; ++m)
            #pragma unroll
            for (int n = 0; n < 4; ++n)
                acc[m][n] = __builtin_amdgcn_mfma_f32_16x16x32_bf16(af[m], bfr[n], acc[m][n], 0, 0, 0);
    }

    // d(row, col): row = iw + m*16 + q*4 + v, col = jw + n*16 + x
    float tq[16], sq4[4];
    #pragma unroll
    for (int m = 0; m < 4; ++m)
        #pragma unroll
        for (int v = 0; v < 4; ++v)
            tq[m * 4 + v] = g_tsqr[b][iw + m * 16 + q * 4 + v];
    #pragma unroll
    for (int n = 0; n < 4; ++n) sq4[n] = g_ssqr[b][jw + n * 16 + x];

    if (PASS == 1) {
        float rmin[16], cmin[4];
        #pragma unroll
        for (int t = 0; t < 16; ++t) rmin[t] = 3.0e38f;
        #pragma unroll
        for (int n = 0; n < 4; ++n) cmin[n] = 3.0e38f;
        #pragma unroll
        for (int m = 0; m < 4; ++m)
            #pragma unroll
            for (int n = 0; n < 4; ++n) {
                float dv[4];
                #pragma unroll
                for (int v = 0; v < 4; ++v) {
                    dv[v] = fmaxf(tq[m * 4 + v] + sq4[n] - 2.f * acc[m][n][v], 0.f);
                    rmin[m * 4 + v] = fminf(rmin[m * 4 + v], dv[v]);
                }
                cmin[n] = fminf(cmin[n], fminf(fminf(dv[0], dv[1]), fminf(dv[2], dv[3])));
            }
        #pragma unroll
        for (int off = 1; off < 16; off <<= 1)
            #pragma unroll
            for (int t = 0; t < 16; ++t) rmin[t] = fminf(rmin[t], __shfl_xor(rmin[t], off));
        if (x == 0)
            #pragma unroll
            for (int t = 0; t < 16; ++t)
                atomicMin(&g_rowmin[b][iw + (t >> 2) * 16 + q * 4 + (t & 3)], __float_as_uint(rmin[t]));
        #pragma unroll
        for (int off = 16; off < 64; off <<= 1)
            #pragma unroll
            for (int n = 0; n < 4; ++n) cmin[n] = fminf(cmin[n], __shfl_xor(cmin[n], off));
        if (q == 0)
            #pragma unroll
            for (int n = 0; n < 4; ++n)
                atomicMin(&g_colmin[b][jw + n * 16 + x], __float_as_uint(cmin[n]));
    }

    if (PASS == 2) {
        float rr[16], rc[4];
        #pragma unroll
        for (int t = 0; t < 16; ++t)
            rr[t] = 2.f / (__uint_as_float(g_rowmin[b][iw + (t >> 2) * 16 + q * 4 + (t & 3)]) + 1e-5f);
        #pragma unroll
        for (int n = 0; n < 4; ++n)
            rc[n] = 2.f / (__uint_as_float(g_colmin[b][jw + n * 16 + x]) + 1e-5f);
        float rs[16], cs[4];
        #pragma unroll
        for (int t = 0; t < 16; ++t) rs[t] = 0.f;
        #pragma unroll
        for (int n = 0; n < 4; ++n) cs[n] = 0.f;
        #pragma unroll
        for (int m = 0; m < 4; ++m)
            #pragma unroll
            for (int n = 0; n < 4; ++n)
                #pragma unroll
                for (int v = 0; v < 4; ++v) {
                    float dv = fmaxf(tq[m * 4 + v] + sq4[n] - 2.f * acc[m][n][v], 0.f);
                    cs[n]        += exp2f((2.f - dv * rc[n]) * L2E);
                    rs[m * 4 + v] += exp2f((2.f - dv * rr[m * 4 + v]) * L2E);
                }
        #pragma unroll
        for (int off = 1; off < 16; off <<= 1)
            #pragma unroll
            for (int t = 0; t < 16; ++t) rs[t] += __shfl_xor(rs[t], off);
        if (x == 0)
            #pragma unroll
            for (int t = 0; t < 16; ++t)
                atomicAdd(&g_ZB[b][iw + (t >> 2) * 16 + q * 4 + (t & 3)], rs[t]);
        #pragma unroll
        for (int off = 16; off < 64; off <<= 1)
            #pragma unroll
            for (int n = 0; n < 4; ++n) cs[n] += __shfl_xor(cs[n], off);
        if (q == 0)
            #pragma unroll
            for (int n = 0; n < 4; ++n)
                atomicAdd(&g_ZA[b][jw + n * 16 + x], cs[n]);
    }

    if (PASS == 3) {
        float rr[16], rc[4], rzb[16], rza[4];
        #pragma unroll
        for (int t = 0; t < 16; ++t) {
            int row = iw + (t >> 2) * 16 + q * 4 + (t & 3);
            rr[t]  = 2.f / (__uint_as_float(g_rowmin[b][row]) + 1e-5f);
            rzb[t] = 1.f / g_ZB[b][row];
        }
        #pragma unroll
        for (int n = 0; n < 4; ++n) {
            int col = jw + n * 16 + x;
            rc[n]  = 2.f / (__uint_as_float(g_colmin[b][col]) + 1e-5f);
            rza[n] = 1.f / g_ZA[b][col];
        }
        float rmx[16], cmx[4];
        #pragma unroll
        for (int t = 0; t < 16; ++t) rmx[t] = 0.f;
        #pragma unroll
        for (int n = 0; n < 4; ++n) cmx[n] = 0.f;
        #pragma unroll
        for (int m = 0; m < 4; ++m)
            #pragma unroll
            for (int n = 0; n < 4; ++n)
                #pragma unroll
                for (int v = 0; v < 4; ++v) {
                    float dv = fmaxf(tq[m * 4 + v] + sq4[n] - 2.f * acc[m][n][v], 0.f);
                    float ea = exp2f((2.f - dv * rc[n]) * L2E) * rza[n];
                    float eb = exp2f((2.f - dv * rr[m * 4 + v]) * L2E) * rzb[m * 4 + v];
                    rmx[m * 4 + v] = fmaxf(rmx[m * 4 + v], ea);
                    cmx[n]         = fmaxf(cmx[n], eb);
                }
        #pragma unroll
        for (int off = 1; off < 16; off <<= 1)
            #pragma unroll
            for (int t = 0; t < 16; ++t) rmx[t] = fmaxf(rmx[t], __shfl_xor(rmx[t], off));
        if (x == 0)
            #pragma unroll
            for (int t = 0; t < 16; ++t)
                atomicMax(&g_mA[b][iw + (t >> 2) * 16 + q * 4 + (t & 3)], __float_as_uint(rmx[t]));
        #pragma unroll
        for (int off = 16; off < 64; off <<= 1)
            #pragma unroll
            for (int n = 0; n < 4; ++n) cmx[n] = fmaxf(cmx[n], __shfl_xor(cmx[n], off));
        if (q == 0)
            #pragma unroll
            for (int n = 0; n < 4; ++n)
                atomicMax(&g_mB[b][jw + n * 16 + x], __float_as_uint(cmx[n]));
    }
}

__global__ void final_kernel(float* __restrict__ out) {
    int tid = threadIdx.x;
    float s[4] = {0.f, 0.f, 0.f, 0.f};
    for (int i = tid; i < NN; i += 256) {
        s[0] += __uint_as_float(g_mA[0][i]);
        s[1] += __uint_as_float(g_mA[1][i]);
        s[2] += __uint_as_float(g_mB[0][i]);
        s[3] += __uint_as_float(g_mB[1][i]);
    }
    __shared__ float red[4][4];
    int lane = tid & 63, w = tid >> 6;
    #pragma unroll
    for (int t = 0; t < 4; ++t) {
        float v = s[t];
        #pragma unroll
        for (int off = 32; off; off >>= 1) v += __shfl_down(v, off);
        if (lane == 0) red[t][w] = v;
    }
    __syncthreads();
    if (tid == 0) {
        float o = 0.f;
        #pragma unroll
        for (int t = 0; t < 4; ++t) {
            float S = (red[t][0] + red[t][1] + red[t][2] + red[t][3]) * (1.f / (float)NN);
            o += -logf(S);
        }
        out[0] = o * 0.25f;
    }
}

extern "C" void kernel_launch(void* const* d_in, const int* in_sizes, int n_in,
                              void* d_out, int out_size, void* d_ws, size_t ws_size,
                              hipStream_t stream) {
    const float* src = (const float*)d_in[0];
    const float* tgt = (const float*)d_in[1];
    (void)in_sizes; (void)n_in; (void)d_ws; (void)ws_size; (void)out_size;

    transpose_prep<<<256, 256, 0, stream>>>(src, tgt);
    init_kernel<<<32, 256, 0, stream>>>();
    sweep_kernel<1><<<2048, 256, 0, stream>>>();
    sweep_kernel<2><<<2048, 256, 0, stream>>>();
    sweep_kernel<3><<<2048, 256, 0, stream>>>();
    final_kernel<<<1, 256, 0, stream>>>((float*)d_out);
}

// Round 4
// 161.678 us; speedup vs baseline: 1.5635x; 1.5635x over previous
//
#include <hip/hip_runtime.h>
#include <math.h>

#define NB 2
#define NC 128
#define NN 4096
#define L2E 1.44269504088896340736f
#define C2L 2.88539008177792681472f   // 2*log2(e)

typedef __attribute__((ext_vector_type(8))) short short8;
typedef __attribute__((ext_vector_type(4))) float f32x4;

// bf16 inputs, transposed to [n][k] with chunk-XOR swizzle baked in:
// 16B-chunk c of row n is stored at chunk (c ^ (n&7)).
__device__ unsigned short g_Tb[NB][NN][NC];
__device__ unsigned short g_Sb[NB][NN][NC];
__device__ float g_tsqr[NB][NN];
__device__ float g_ssqr[NB][NN];
__device__ float g_rowS[NB][NN];    // -(2/(rowmin+eps))*L2E
__device__ float g_rowLZ[NB][NN];   // log2(ZB)
__device__ float g_rowE[NB][NN];    // exp2(max arg) = mA
__device__ float g_colS[NB][NN];
__device__ float g_colLZ[NB][NN];
__device__ float g_colE[NB][NN];
__device__ float g_colpart[NB][128][NN];  // per-stripe col partials (4MB)
__device__ float g_rowpart[NB][2][NN];    // per-jhalf row partials

#if __has_builtin(__builtin_amdgcn_exp2f)
__device__ __forceinline__ float fexp2(float x) { return __builtin_amdgcn_exp2f(x); }
#else
__device__ __forceinline__ float fexp2(float x) { return exp2f(x); }
#endif

#define GLL16(gsrc, ldst) \
  __builtin_amdgcn_global_load_lds((const __attribute__((address_space(1))) void*)(gsrc), \
                                   (__attribute__((address_space(3))) void*)(ldst), 16, 0, 0)

__device__ __forceinline__ unsigned f2bf(float f) {
    unsigned u = __float_as_uint(f);
    u += 0x7FFFu + ((u >> 16) & 1u);   // RNE
    return u >> 16;
}

// fp32 [k][n] -> swizzled bf16 [n][k], fused with squared-norm computation.
__global__ void __launch_bounds__(256) transpose_prep(const float* __restrict__ src,
                                                      const float* __restrict__ tgt) {
    __shared__ float ls[NC][68];
    int bid = blockIdx.x;              // 2 mat x 2 b x 64 n-chunks = 256
    int mat = bid >> 7;
    int b   = (bid >> 6) & 1;
    int n0  = (bid & 63) << 6;
    int tid = threadIdx.x;
    const float* in = (mat ? tgt : src) + (size_t)b * NC * NN;
    unsigned short (*out)[NC] = mat ? g_Tb[b] : g_Sb[b];
    float* sq = mat ? g_tsqr[b] : g_ssqr[b];

    for (int idx = tid; idx < NC * 16; idx += 256) {
        int k = idx >> 4, c4 = (idx & 15) << 2;
        *(float4*)&ls[k][c4] = *(const float4*)(in + (size_t)k * NN + n0 + c4);
    }
    __syncthreads();
    {
        int n = tid & 63, c = tid >> 6;
        for (int cc = c; cc < 16; cc += 4) {
            unsigned uo[4];
            #pragma unroll
            for (int e = 0; e < 4; ++e) {
                unsigned lo = f2bf(ls[cc * 8 + 2 * e][n]);
                unsigned hi = f2bf(ls[cc * 8 + 2 * e + 1][n]);
                uo[e] = lo | (hi << 16);
            }
            *(uint4*)&out[n0 + n][(cc ^ (n & 7)) * 8] = make_uint4(uo[0], uo[1], uo[2], uo[3]);
        }
    }
    if (tid < 64) {
        float s = 0.f;
        #pragma unroll 8
        for (int k = 0; k < NC; ++k) { float v = ls[k][tid]; s = fmaf(v, v, s); }
        sq[n0 + tid] = s;
    }
}

// Stripe sweep: block owns 32 T-rows x 2048 S-cols. Row reductions in regs
// (exclusive store to g_rowpart), col reductions to g_colpart. No atomics.
template<int PASS>
__global__ void __launch_bounds__(256) sweep_kernel() {
    __shared__ unsigned short Tl[32 * 128];        // 8KB  (swizzled image)
    __shared__ unsigned short Sl[2][64 * 128];     // 32KB double-buffered
    __shared__ float redrow[4][32];

    int bid    = blockIdx.x;           // 512
    int b      = bid >> 8;
    int stripe = (bid >> 1) & 127;
    int jh     = bid & 1;
    int i0     = stripe * 32;
    int jbase  = jh * 2048;
    int tid = threadIdx.x;
    int w = tid >> 6, lane = tid & 63, q = lane >> 4, x = lane & 15;

    // stage T stripe (512 x 16B chunks) + S tile 0 (1024 chunks)
    {
        int c0 = tid, c1 = tid + 256;
        GLL16(&g_Tb[b][i0 + (c0 >> 4)][(c0 & 15) * 8], &Tl[c0 * 8]);
        GLL16(&g_Tb[b][i0 + (c1 >> 4)][(c1 & 15) * 8], &Tl[c1 * 8]);
    }
    #pragma unroll
    for (int kch = 0; kch < 4; ++kch) {
        int c = tid + kch * 256;
        GLL16(&g_Sb[b][jbase + (c >> 4)][(c & 15) * 8], &Sl[0][c * 8]);
    }

    // hoisted per-row data (rows i0 + m*16 + q*4 + v)
    float tq[8], rS[8], rC[8];
    #pragma unroll
    for (int m = 0; m < 2; ++m)
        #pragma unroll
        for (int v = 0; v < 4; ++v) {
            int row = i0 + m * 16 + q * 4 + v;
            tq[m * 4 + v] = g_tsqr[b][row];
            if (PASS >= 2) rS[m * 4 + v] = g_rowS[b][row];
            if (PASS == 3) rC[m * 4 + v] = C2L - g_rowLZ[b][row];
        }
    // aux prefetch for tile 0 (per-col data)
    float sq_n = g_ssqr[b][jbase + w * 16 + x];
    float cS_n = 0.f, cC_n = 0.f;
    if (PASS >= 2) cS_n = g_colS[b][jbase + w * 16 + x];
    if (PASS == 3) cC_n = C2L - g_colLZ[b][jbase + w * 16 + x];

    float rstate[8];
    #pragma unroll
    for (int e = 0; e < 8; ++e)
        rstate[e] = (PASS == 1) ? 3.0e38f : (PASS == 2 ? 0.f : -3.0e38f);

    __syncthreads();   // vmcnt(0): T + S0 staged

    // hoisted A-fragments (same rows for every j-tile)
    short8 af[2][4];
    #pragma unroll
    for (int m = 0; m < 2; ++m)
        #pragma unroll
        for (int kk = 0; kk < 4; ++kk) {
            int row = m * 16 + x;
            int ch  = (kk * 4 + q) ^ (x & 7);
            af[m][kk] = *(const short8*)&Tl[row * 128 + ch * 8];
        }

    int cur = 0;
    for (int jt = 0; jt < 32; ++jt) {
        if (jt < 31) {
            #pragma unroll
            for (int kch = 0; kch < 4; ++kch) {
                int c = tid + kch * 256;
                GLL16(&g_Sb[b][jbase + (jt + 1) * 64 + (c >> 4)][(c & 15) * 8],
                      &Sl[cur ^ 1][c * 8]);
            }
        }
        float sq_c = sq_n, cS_c = cS_n, cC_c = cC_n;
        if (jt < 31) {
            int coln = jbase + (jt + 1) * 64 + w * 16 + x;
            sq_n = g_ssqr[b][coln];
            if (PASS >= 2) cS_n = g_colS[b][coln];
            if (PASS == 3) cC_n = C2L - g_colLZ[b][coln];
        }

        short8 bf[4];
        #pragma unroll
        for (int kk = 0; kk < 4; ++kk) {
            int r  = w * 16 + x;
            int ch = (kk * 4 + q) ^ (x & 7);
            bf[kk] = *(const short8*)&Sl[cur][r * 128 + ch * 8];
        }
        f32x4 acc0 = {0.f, 0.f, 0.f, 0.f}, acc1 = {0.f, 0.f, 0.f, 0.f};
        #pragma unroll
        for (int kk = 0; kk < 4; ++kk) {
            acc0 = __builtin_amdgcn_mfma_f32_16x16x32_bf16(af[0][kk], bf[kk], acc0, 0, 0, 0);
            acc1 = __builtin_amdgcn_mfma_f32_16x16x32_bf16(af[1][kk], bf[kk], acc1, 0, 0, 0);
        }

        float colval;
        if (PASS == 1) {
            colval = 3.0e38f;
            #pragma unroll
            for (int m = 0; m < 2; ++m)
                #pragma unroll
                for (int v = 0; v < 4; ++v) {
                    float a = (m == 0) ? acc0[v] : acc1[v];
                    float dv = fmaxf(fmaf(-2.f, a, tq[m * 4 + v] + sq_c), 0.f);
                    rstate[m * 4 + v] = fminf(rstate[m * 4 + v], dv);
                    colval = fminf(colval, dv);
                }
            colval = fminf(colval, __shfl_xor(colval, 16));
            colval = fminf(colval, __shfl_xor(colval, 32));
        } else if (PASS == 2) {
            colval = 0.f;
            #pragma unroll
            for (int m = 0; m < 2; ++m)
                #pragma unroll
                for (int v = 0; v < 4; ++v) {
                    float a = (m == 0) ? acc0[v] : acc1[v];
                    float dv = fmaxf(fmaf(-2.f, a, tq[m * 4 + v] + sq_c), 0.f);
                    colval            += fexp2(fmaf(dv, cS_c, C2L));
                    rstate[m * 4 + v] += fexp2(fmaf(dv, rS[m * 4 + v], C2L));
                }
            colval += __shfl_xor(colval, 16);
            colval += __shfl_xor(colval, 32);
        } else {
            colval = -3.0e38f;
            #pragma unroll
            for (int m = 0; m < 2; ++m)
                #pragma unroll
                for (int v = 0; v < 4; ++v) {
                    float a = (m == 0) ? acc0[v] : acc1[v];
                    float dv = fmaxf(fmaf(-2.f, a, tq[m * 4 + v] + sq_c), 0.f);
                    float uA = fmaf(dv, cS_c, cC_c);
                    float uB = fmaf(dv, rS[m * 4 + v], rC[m * 4 + v]);
                    rstate[m * 4 + v] = fmaxf(rstate[m * 4 + v], uA);
                    colval = fmaxf(colval, uB);
                }
            colval = fmaxf(colval, __shfl_xor(colval, 16));
            colval = fmaxf(colval, __shfl_xor(colval, 32));
        }
        if (q == 0)
            g_colpart[b][stripe][jbase + jt * 64 + w * 16 + x] = colval;
        __syncthreads();
        cur ^= 1;
    }

    // row reduction: over x-lanes, then over waves via LDS
    #pragma unroll
    for (int off = 1; off < 16; off <<= 1)
        #pragma unroll
        for (int e = 0; e < 8; ++e) {
            float o = __shfl_xor(rstate[e], off);
            rstate[e] = (PASS == 1) ? fminf(rstate[e], o)
                       : (PASS == 2) ? rstate[e] + o : fmaxf(rstate[e], o);
        }
    if (x == 0)
        #pragma unroll
        for (int e = 0; e < 8; ++e)
            redrow[w][(e >> 2) * 16 + q * 4 + (e & 3)] = rstate[e];
    __syncthreads();
    if (tid < 32) {
        float a = redrow[0][tid], c = redrow[1][tid], d = redrow[2][tid], e = redrow[3][tid];
        float v = (PASS == 1) ? fminf(fminf(a, c), fminf(d, e))
                 : (PASS == 2) ? (a + c) + (d + e)
                 : fmaxf(fmaxf(a, c), fmaxf(d, e));
        g_rowpart[b][jh][i0 + tid] = v;
    }
}

template<int PASS>
__global__ void __launch_bounds__(256) reduce_kernel() {
    int bid = blockIdx.x;             // 32
    int b = bid >> 4, ch = bid & 15;
    int tid = threadIdx.x;
    int col = ch * 256 + tid;
    float acc = (PASS == 1) ? 3.0e38f : (PASS == 2 ? 0.f : -3.0e38f);
    for (int s = 0; s < 128; ++s) {
        float v = g_colpart[b][s][col];
        acc = (PASS == 1) ? fminf(acc, v) : (PASS == 2) ? acc + v : fmaxf(acc, v);
    }
    if (PASS == 1) g_colS[b][col]  = -(C2L / (acc + 1e-5f));
    if (PASS == 2) g_colLZ[b][col] = log2f(acc);
    if (PASS == 3) g_colE[b][col]  = fexp2(acc);

    int r = col;
    float p0 = g_rowpart[b][0][r], p1 = g_rowpart[b][1][r];
    float rv = (PASS == 1) ? fminf(p0, p1) : (PASS == 2) ? p0 + p1 : fmaxf(p0, p1);
    if (PASS == 1) g_rowS[b][r]  = -(C2L / (rv + 1e-5f));
    if (PASS == 2) g_rowLZ[b][r] = log2f(rv);
    if (PASS == 3) g_rowE[b][r]  = fexp2(rv);
}

__global__ void final_kernel(float* __restrict__ out) {
    int tid = threadIdx.x;
    float s[4] = {0.f, 0.f, 0.f, 0.f};
    for (int i = tid; i < NN; i += 256) {
        s[0] += g_rowE[0][i];
        s[1] += g_rowE[1][i];
        s[2] += g_colE[0][i];
        s[3] += g_colE[1][i];
    }
    __shared__ float red[4][4];
    int lane = tid & 63, w = tid >> 6;
    #pragma unroll
    for (int t = 0; t < 4; ++t) {
        float v = s[t];
        #pragma unroll
        for (int off = 32; off; off >>= 1) v += __shfl_down(v, off);
        if (lane == 0) red[t][w] = v;
    }
    __syncthreads();
    if (tid == 0) {
        float o = 0.f;
        #pragma unroll
        for (int t = 0; t < 4; ++t) {
            float S = red[t][0] + red[t][1] + red[t][2] + red[t][3];
            o += logf(S);
        }
        out[0] = logf((float)NN) - 0.25f * o;
    }
}

extern "C" void kernel_launch(void* const* d_in, const int* in_sizes, int n_in,
                              void* d_out, int out_size, void* d_ws, size_t ws_size,
                              hipStream_t stream) {
    const float* src = (const float*)d_in[0];
    const float* tgt = (const float*)d_in[1];
    (void)in_sizes; (void)n_in; (void)d_ws; (void)ws_size; (void)out_size;

    transpose_prep<<<256, 256, 0, stream>>>(src, tgt);
    sweep_kernel<1><<<512, 256, 0, stream>>>();
    reduce_kernel<1><<<32, 256, 0, stream>>>();
    sweep_kernel<2><<<512, 256, 0, stream>>>();
    reduce_kernel<2><<<32, 256, 0, stream>>>();
    sweep_kernel<3><<<512, 256, 0, stream>>>();
    reduce_kernel<3><<<32, 256, 0, stream>>>();
    final_kernel<<<1, 256, 0, stream>>>((float*)d_out);
}